// Round 3
// baseline (9670.734 us; speedup 1.0000x reference)
//
#include <hip/hip_runtime.h>
#include <hip/hip_bf16.h>

#define Bsz 64
#define Tsz 512
#define Isz 512
#define Hsz 512

// ---------------- Phase 1: xU = x @ U + bias ----------------
// M = B*T = 32768, K = 512, N = 512. Tile 128x64, BK=32, 256 threads, 8x4 micro.
__global__ __launch_bounds__(256) void p1_gemm(const float* __restrict__ X,
                                               const float* __restrict__ U,
                                               const float* __restrict__ bias,
                                               float* __restrict__ out) {
  const int K = Isz, N = Hsz;
  __shared__ float As[32][128];
  __shared__ float Bs[32][64];
  const int MB = (Bsz * Tsz) / 128;
  int bm = blockIdx.x & (MB - 1);
  int bn = blockIdx.x >> 8;
  int t = threadIdx.x;
  int tx = t & 15, ty = t >> 4;

  float acc[8][4];
#pragma unroll
  for (int r = 0; r < 8; r++)
#pragma unroll
    for (int c = 0; c < 4; c++) acc[r][c] = 0.f;

  const float* Xb = X + (size_t)bm * 128 * K;
  const float* Ub = U + bn * 64;

  for (int k0 = 0; k0 < K; k0 += 32) {
    int ar = t >> 3, aq = t & 7;
#pragma unroll
    for (int i = 0; i < 4; i++) {
      int row = ar + 32 * i;
      float4 v = *(const float4*)&Xb[(size_t)row * K + k0 + 4 * aq];
      As[4 * aq + 0][row] = v.x;
      As[4 * aq + 1][row] = v.y;
      As[4 * aq + 2][row] = v.z;
      As[4 * aq + 3][row] = v.w;
    }
    int bkk = t >> 4, bq = t & 15;
#pragma unroll
    for (int i = 0; i < 2; i++) {
      int kk = bkk + 16 * i;
      *(float4*)&Bs[kk][4 * bq] = *(const float4*)&Ub[(size_t)(k0 + kk) * N + 4 * bq];
    }
    __syncthreads();
#pragma unroll
    for (int kk = 0; kk < 32; kk++) {
      float4 A0 = *(const float4*)&As[kk][ty * 8];
      float4 A1 = *(const float4*)&As[kk][ty * 8 + 4];
      float4 B0 = *(const float4*)&Bs[kk][tx * 4];
      float av[8] = {A0.x, A0.y, A0.z, A0.w, A1.x, A1.y, A1.z, A1.w};
      float bv[4] = {B0.x, B0.y, B0.z, B0.w};
#pragma unroll
      for (int r = 0; r < 8; r++)
#pragma unroll
        for (int c = 0; c < 4; c++) acc[r][c] += av[r] * bv[c];
    }
    __syncthreads();
  }

  float4 bias4 = *(const float4*)&bias[bn * 64 + tx * 4];
  float bb[4] = {bias4.x, bias4.y, bias4.z, bias4.w};
#pragma unroll
  for (int r = 0; r < 8; r++) {
    float4 o;
    o.x = acc[r][0] + bb[0];
    o.y = acc[r][1] + bb[1];
    o.z = acc[r][2] + bb[2];
    o.w = acc[r][3] + bb[3];
    *(float4*)&out[((size_t)bm * 128 + ty * 8 + r) * N + bn * 64 + tx * 4] = o;
  }
}

// ---------------- Phase 2: recurrence, V in REGISTERS ----------------
// 32 groups x 8 blocks; group g owns batches {2g, 2g+1}. Block j owns V
// columns [64j,64j+64). Thread (c = t>>3, ks = t&7) keeps V[ks*64..+63][col]
// in 16 NAMED float4 registers (no array -> no scratch, rule #20).
// h (2x512 fp32) lives in LDS, XOR-swizzled (pure function of k) so each
// wave's h4 read covers 8 distinct bank-quads (broadcast over the 8 c-lanes).
// Cross-block exchange per step: owners store h-slice as relaxed agent-scope
// atomics (straight to coherence point), __syncthreads (drains vmcnt),
// t0 release-stores per-block flag, every wave polls the 8 flags (8 lanes),
// acquire fence, plain float2 loads of the full group h, swizzled ds_write.
// Group members share bid%8 -> same-XCD heuristic; fences keep it correct
// regardless. 256 blocks @ 1/CU -> co-resident -> spin sync deadlock-free.
#define NGrp 32
#define BPGrp 8

__device__ __forceinline__ float ftanh(float x) {
  float ax = fabsf(x);
  float e = __expf(2.f * ax);
  float r = 1.f - 2.f / (e + 1.f);
  return copysignf(r, x);
}

__device__ __forceinline__ int hswz(int k) {  // bank swizzle, function of k only
  return k ^ (((k >> 6) & 7) << 2);
}

__global__ __launch_bounds__(512, 2) void p2_rnn(const float* __restrict__ h0,
                                                 const float* __restrict__ V,
                                                 float* __restrict__ out,
                                                 float* __restrict__ ws) {
  int* flags = (int*)ws;       // 32*8 ints, zeroed at launch
  float* hbuf = ws + 256;      // [2][64][512] double buffer

  int bid = blockIdx.x;
  int g = bid & 31;            // group; members share bid%8 (same XCD likely)
  int j = bid >> 5;            // 0..7 position in group
  int t = threadIdx.x;
  int c = t >> 3, ks = t & 7, lane = t & 63;
  int col = 64 * j + c;

  __shared__ float hs[2][Hsz];  // 4 KB, swizzled

  // ---- V slice into 16 named float4 registers (column gather, one-time)
#define DECLV(i)                                                        \
  float4 v##i;                                                          \
  {                                                                     \
    size_t k0 = (size_t)(ks * 64 + 4 * (i));                            \
    v##i.x = V[(k0 + 0) * Hsz + col];                                   \
    v##i.y = V[(k0 + 1) * Hsz + col];                                   \
    v##i.z = V[(k0 + 2) * Hsz + col];                                   \
    v##i.w = V[(k0 + 3) * Hsz + col];                                   \
  }
  DECLV(0) DECLV(1) DECLV(2) DECLV(3) DECLV(4) DECLV(5) DECLV(6) DECLV(7)
  DECLV(8) DECLV(9) DECLV(10) DECLV(11) DECLV(12) DECLV(13) DECLV(14) DECLV(15)
#undef DECLV

  // ---- initial h from h0 (batches 2g, 2g+1), swizzled into LDS
  {
    int idx = 2 * t;
    int b = idx >> 9, k = idx & 511;
    float2 hv = *(const float2*)&h0[(size_t)(2 * g + b) * Hsz + k];
    *(float2*)&hs[b][hswz(k)] = hv;
  }
  __syncthreads();

  bool owner = (ks == 0);
  size_t ob0 = ((size_t)(2 * g + 0) * Tsz) * Hsz + col;
  size_t ob1 = ((size_t)(2 * g + 1) * Tsz) * Hsz + col;
  float xu0 = 0.f, xu1 = 0.f;
  if (owner) { xu0 = out[ob0]; xu1 = out[ob1]; }

  for (int s = 0; s < Tsz; s++) {
    // prefetch next xU early (hides L2/L3 latency under the FMAs)
    float xn0 = 0.f, xn1 = 0.f;
    if (owner && s + 1 < Tsz) {
      xn0 = out[ob0 + (size_t)(s + 1) * Hsz];
      xn1 = out[ob1 + (size_t)(s + 1) * Hsz];
    }

    float a00 = 0.f, a01 = 0.f, a02 = 0.f, a03 = 0.f;
    float a10 = 0.f, a11 = 0.f, a12 = 0.f, a13 = 0.f;
#define FMA_I(i)                                                        \
  {                                                                     \
    int kf = ks * 64 + ((4 * (i)) ^ (ks << 2));                         \
    float4 hA = *(const float4*)&hs[0][kf];                             \
    float4 hB = *(const float4*)&hs[1][kf];                             \
    a00 += v##i.x * hA.x; a01 += v##i.y * hA.y;                         \
    a02 += v##i.z * hA.z; a03 += v##i.w * hA.w;                         \
    a10 += v##i.x * hB.x; a11 += v##i.y * hB.y;                         \
    a12 += v##i.z * hB.z; a13 += v##i.w * hB.w;                         \
  }
    FMA_I(0) FMA_I(1) FMA_I(2) FMA_I(3) FMA_I(4) FMA_I(5) FMA_I(6) FMA_I(7)
    FMA_I(8) FMA_I(9) FMA_I(10) FMA_I(11) FMA_I(12) FMA_I(13) FMA_I(14) FMA_I(15)
#undef FMA_I

    float r0 = (a00 + a01) + (a02 + a03);
    float r1 = (a10 + a11) + (a12 + a13);
    r0 += __shfl_xor(r0, 1); r0 += __shfl_xor(r0, 2); r0 += __shfl_xor(r0, 4);
    r1 += __shfl_xor(r1, 1); r1 += __shfl_xor(r1, 2); r1 += __shfl_xor(r1, 4);

    int p = (s + 1) & 1;
    if (owner) {
      float h0v = ftanh(r0 + xu0);
      float h1v = ftanh(r1 + xu1);
      out[ob0 + (size_t)s * Hsz] = h0v;
      out[ob1 + (size_t)s * Hsz] = h1v;
      if (s + 1 < Tsz) {
        __hip_atomic_store(&hbuf[((size_t)p * Bsz + 2 * g + 0) * Hsz + col], h0v,
                           __ATOMIC_RELAXED, __HIP_MEMORY_SCOPE_AGENT);
        __hip_atomic_store(&hbuf[((size_t)p * Bsz + 2 * g + 1) * Hsz + col], h1v,
                           __ATOMIC_RELAXED, __HIP_MEMORY_SCOPE_AGENT);
      }
    }
    xu0 = xn0; xu1 = xn1;

    if (s + 1 < Tsz) {
      __syncthreads();  // drains vmcnt: all owners' hbuf stores are visible
      if (t == 0)
        __hip_atomic_store(&flags[g * BPGrp + j], s + 1, __ATOMIC_RELEASE,
                           __HIP_MEMORY_SCOPE_AGENT);
      // every wave polls the group's 8 flags with 8 lanes
      int target = s + 1;
      int guard = 0;
      while (true) {
        int f = (lane < BPGrp)
                    ? __hip_atomic_load(&flags[g * BPGrp + lane], __ATOMIC_RELAXED,
                                        __HIP_MEMORY_SCOPE_AGENT)
                    : target;
        if (__all(f >= target)) break;
        if (++guard > (1 << 22)) break;  // anti-hang: fail loud, not silent
      }
      __builtin_amdgcn_fence(__ATOMIC_ACQUIRE, "agent");
      {
        int idx = 2 * t;
        int b = idx >> 9, k = idx & 511;
        float2 hv =
            *(const float2*)&hbuf[((size_t)p * Bsz + 2 * g + b) * Hsz + k];
        *(float2*)&hs[b][hswz(k)] = hv;
      }
      __syncthreads();
    }
  }
}

extern "C" void kernel_launch(void* const* d_in, const int* in_sizes, int n_in,
                              void* d_out, int out_size, void* d_ws, size_t ws_size,
                              hipStream_t stream) {
  const float* x  = (const float*)d_in[0];
  const float* h0 = (const float*)d_in[1];
  const float* U  = (const float*)d_in[2];
  const float* V  = (const float*)d_in[3];
  const float* b  = (const float*)d_in[4];
  float* out = (float*)d_out;
  float* ws  = (float*)d_ws;

  // zero the 256 per-block flags (ws is re-poisoned to 0xAA before every launch)
  hipMemsetAsync(d_ws, 0, NGrp * BPGrp * sizeof(int), stream);

  // Phase 1: out = x @ U + b
  p1_gemm<<<dim3(2048), dim3(256), 0, stream>>>(x, U, b, out);

  // Phase 2: in-place recurrence over T
  p2_rnn<<<dim3(256), dim3(512), 0, stream>>>(h0, V, out, ws);
}

// Round 4
// 1472.108 us; speedup vs baseline: 6.5693x; 6.5693x over previous
//
#include <hip/hip_runtime.h>
#include <hip/hip_bf16.h>

#define Bsz 64
#define Tsz 512
#define Isz 512
#define Hsz 512

// ---------------- Phase 1: xU = x @ U + bias ----------------
// M = B*T = 32768, K = 512, N = 512. Tile 128x64, BK=32, 256 threads, 8x4 micro.
__global__ __launch_bounds__(256) void p1_gemm(const float* __restrict__ X,
                                               const float* __restrict__ U,
                                               const float* __restrict__ bias,
                                               float* __restrict__ out) {
  const int K = Isz, N = Hsz;
  __shared__ float As[32][128];
  __shared__ float Bs[32][64];
  const int MB = (Bsz * Tsz) / 128;
  int bm = blockIdx.x & (MB - 1);
  int bn = blockIdx.x >> 8;
  int t = threadIdx.x;
  int tx = t & 15, ty = t >> 4;

  float acc[8][4];
#pragma unroll
  for (int r = 0; r < 8; r++)
#pragma unroll
    for (int c = 0; c < 4; c++) acc[r][c] = 0.f;

  const float* Xb = X + (size_t)bm * 128 * K;
  const float* Ub = U + bn * 64;

  for (int k0 = 0; k0 < K; k0 += 32) {
    int ar = t >> 3, aq = t & 7;
#pragma unroll
    for (int i = 0; i < 4; i++) {
      int row = ar + 32 * i;
      float4 v = *(const float4*)&Xb[(size_t)row * K + k0 + 4 * aq];
      As[4 * aq + 0][row] = v.x;
      As[4 * aq + 1][row] = v.y;
      As[4 * aq + 2][row] = v.z;
      As[4 * aq + 3][row] = v.w;
    }
    int bkk = t >> 4, bq = t & 15;
#pragma unroll
    for (int i = 0; i < 2; i++) {
      int kk = bkk + 16 * i;
      *(float4*)&Bs[kk][4 * bq] = *(const float4*)&Ub[(size_t)(k0 + kk) * N + 4 * bq];
    }
    __syncthreads();
#pragma unroll
    for (int kk = 0; kk < 32; kk++) {
      float4 A0 = *(const float4*)&As[kk][ty * 8];
      float4 A1 = *(const float4*)&As[kk][ty * 8 + 4];
      float4 B0 = *(const float4*)&Bs[kk][tx * 4];
      float av[8] = {A0.x, A0.y, A0.z, A0.w, A1.x, A1.y, A1.z, A1.w};
      float bv[4] = {B0.x, B0.y, B0.z, B0.w};
#pragma unroll
      for (int r = 0; r < 8; r++)
#pragma unroll
        for (int c = 0; c < 4; c++) acc[r][c] += av[r] * bv[c];
    }
    __syncthreads();
  }

  float4 bias4 = *(const float4*)&bias[bn * 64 + tx * 4];
  float bb[4] = {bias4.x, bias4.y, bias4.z, bias4.w};
#pragma unroll
  for (int r = 0; r < 8; r++) {
    float4 o;
    o.x = acc[r][0] + bb[0];
    o.y = acc[r][1] + bb[1];
    o.z = acc[r][2] + bb[2];
    o.w = acc[r][3] + bb[3];
    *(float4*)&out[((size_t)bm * 128 + ty * 8 + r) * N + bn * 64 + tx * 4] = o;
  }
}

// ---------------- Phase 2: recurrence — V in LDS, tagged-atom sync ----------
// 32 groups x 8 blocks; group g owns batches {2g,2g+1}; block jb owns V cols
// [64jb, 64jb+64) staged ONCE into 128 KB LDS with a wave-contiguous layout:
//   V4[w][i][ks][cl]  (w=wave, i=k-chunk 0..15, ks=k-split 0..7, cl=col 0..7)
// so at each unroll step i a wave reads a CONTIGUOUS 1 KB chunk -> conflict-
// free full-BW ds_read_b128. h lives in LDS swizzled k^(((k>>6)&7)<<2): the 8
// ks-lanes hit 8 distinct bank-quads, the 8 c-lanes multicast (free).
// Cross-block exchange per step: owner packs (h fp32, step tag) in ONE 8B
// atom, relaxed agent-scope atomic store (straight to the coherence point).
// Every thread polls ITS OWN element's atom until tag==s+1 -> value+tag in
// the same atom means NO acquire fence, NO flag hotspot, no L2 invalidates.
// Double buffer is race-free: writing step s+2 requires all step s+1 polls
// group-wide, which requires all step s polls -> lag is bounded at 2 steps.
// 256 blocks @ 1/CU (132 KB LDS) -> all co-resident -> polls cannot deadlock.
#define NGrp 32
#define BPGrp 8
#define CPB 64
#define HOFFS (CPB * Hsz)  // 32768 floats = 128 KB of V, then 1024 floats h

__device__ __forceinline__ float ftanh(float x) {
  float ax = fabsf(x);
  float e = __expf(2.f * ax);
  float r = 1.f - 2.f / (e + 1.f);
  return copysignf(r, x);
}

__device__ __forceinline__ int hswz(int k) { return k ^ (((k >> 6) & 7) << 2); }

__device__ __forceinline__ unsigned long long packha(float h, int tag) {
  return (unsigned long long)__float_as_uint(h) |
         ((unsigned long long)(unsigned)tag << 32);
}

__global__ __launch_bounds__(512) void p2_rnn(
    const float* __restrict__ h0, const float* __restrict__ V,
    float* __restrict__ out, unsigned long long* __restrict__ atoms) {
  extern __shared__ float sm[];  // [0,32768) V ; [32768, 33792) h
  float4* __restrict__ Vl = (float4*)sm;
  float* __restrict__ hsm = sm + HOFFS;

  int bid = blockIdx.x;
  int g = bid & 31;   // members at bid≡g (mod 32) -> same bid%8 -> same XCD-ish
  int jb = bid >> 5;  // 0..7 column-block
  int t = threadIdx.x;
  int c = t >> 3, ks = t & 7;
  int w = t >> 6, cl = c & 7;

  // ---- stage V: wave reads one contiguous 256B row-segment per rep ----
  for (int rep = 0; rep < 64; rep++) {
    int idx = rep * 512 + t;
    int row = idx >> 6, cc = idx & 63;
    float val = V[(size_t)row * Hsz + CPB * jb + cc];
    int ksr = row >> 6, ir = (row >> 2) & 15, jr = row & 3;
    sm[(cc >> 3) * 4096 + ir * 256 + ksr * 32 + (cc & 7) * 4 + jr] = val;
  }
  // ---- initial h from h0 (batches 2g, 2g+1), swizzled ----
  {
    int k = t;
    hsm[hswz(k)] = h0[(size_t)(2 * g + 0) * Hsz + k];
    hsm[512 + hswz(k)] = h0[(size_t)(2 * g + 1) * Hsz + k];
  }
  __syncthreads();

  bool owner = (ks == 0);
  int col = CPB * jb + c;
  size_t ob0 = ((size_t)(2 * g + 0) * Tsz) * Hsz + col;
  size_t ob1 = ((size_t)(2 * g + 1) * Tsz) * Hsz + col;
  float xu0 = 0.f, xu1 = 0.f;
  if (owner) { xu0 = out[ob0]; xu1 = out[ob1]; }

  const int vbase = w * 1024 + ks * 8 + cl;  // float4 index
  const int swk = ks << 2;
  const int hb = ks * 64;
  const int pk = t;  // this thread's polled element k

  for (int s = 0; s < Tsz; s++) {
    // prefetch next xU early (latency hides under the FMA phase)
    float xn0 = 0.f, xn1 = 0.f;
    if (owner && s + 1 < Tsz) {
      xn0 = out[ob0 + (size_t)(s + 1) * Hsz];
      xn1 = out[ob1 + (size_t)(s + 1) * Hsz];
    }

    float a00 = 0.f, a01 = 0.f, a02 = 0.f, a03 = 0.f;
    float a10 = 0.f, a11 = 0.f, a12 = 0.f, a13 = 0.f;
#pragma unroll
    for (int i = 0; i < 16; i++) {
      float4 v = Vl[vbase + i * 64];  // contiguous 1KB per wave: conflict-free
      int hf = hb + ((4 * i) ^ swk);  // 8 distinct bank-quads over ks
      float4 hA = *(const float4*)&hsm[hf];
      float4 hB = *(const float4*)&hsm[512 + hf];
      a00 += v.x * hA.x; a01 += v.y * hA.y; a02 += v.z * hA.z; a03 += v.w * hA.w;
      a10 += v.x * hB.x; a11 += v.y * hB.y; a12 += v.z * hB.z; a13 += v.w * hB.w;
    }
    float r0 = (a00 + a01) + (a02 + a03);
    float r1 = (a10 + a11) + (a12 + a13);
    r0 += __shfl_xor(r0, 1); r0 += __shfl_xor(r0, 2); r0 += __shfl_xor(r0, 4);
    r1 += __shfl_xor(r1, 1); r1 += __shfl_xor(r1, 2); r1 += __shfl_xor(r1, 4);

    int p = (s + 1) & 1;
    if (owner) {
      float h0v = ftanh(r0 + xu0);
      float h1v = ftanh(r1 + xu1);
      out[ob0 + (size_t)s * Hsz] = h0v;
      out[ob1 + (size_t)s * Hsz] = h1v;
      if (s + 1 < Tsz) {
        __hip_atomic_store(&atoms[((size_t)p * Bsz + 2 * g + 0) * Hsz + col],
                           packha(h0v, s + 1), __ATOMIC_RELAXED,
                           __HIP_MEMORY_SCOPE_AGENT);
        __hip_atomic_store(&atoms[((size_t)p * Bsz + 2 * g + 1) * Hsz + col],
                           packha(h1v, s + 1), __ATOMIC_RELAXED,
                           __HIP_MEMORY_SCOPE_AGENT);
      }
    }
    xu0 = xn0; xu1 = xn1;

    if (s + 1 < Tsz) {
      __syncthreads();  // all local reads of hsm done before overwrite
      unsigned long long* q0 = &atoms[((size_t)p * Bsz + 2 * g + 0) * Hsz + pk];
      unsigned long long* q1 = &atoms[((size_t)p * Bsz + 2 * g + 1) * Hsz + pk];
      int want = s + 1;
      float hv0 = 0.f, hv1 = 0.f;
      bool d0 = false, d1 = false;
      int guard = 0;
      while (true) {
        if (!d0) {
          unsigned long long a = __hip_atomic_load(q0, __ATOMIC_RELAXED,
                                                   __HIP_MEMORY_SCOPE_AGENT);
          if ((int)(a >> 32) == want) { hv0 = __uint_as_float((unsigned)a); d0 = true; }
        }
        if (!d1) {
          unsigned long long a = __hip_atomic_load(q1, __ATOMIC_RELAXED,
                                                   __HIP_MEMORY_SCOPE_AGENT);
          if ((int)(a >> 32) == want) { hv1 = __uint_as_float((unsigned)a); d1 = true; }
        }
        if (d0 && d1) break;
        if (++guard > (1 << 20)) break;  // anti-hang: fail loud, not silent
      }
      hsm[hswz(pk)] = hv0;
      hsm[512 + hswz(pk)] = hv1;
      __syncthreads();
    }
  }
}

extern "C" void kernel_launch(void* const* d_in, const int* in_sizes, int n_in,
                              void* d_out, int out_size, void* d_ws, size_t ws_size,
                              hipStream_t stream) {
  const float* x  = (const float*)d_in[0];
  const float* h0 = (const float*)d_in[1];
  const float* U  = (const float*)d_in[2];
  const float* V  = (const float*)d_in[3];
  const float* b  = (const float*)d_in[4];
  float* out = (float*)d_out;
  // atoms: [2][Bsz][Hsz] x 8B = 512 KB of d_ws. Tags are exact-match (s+1);
  // the 0xAA poison (tag 0xAAAAAAAA) can never match -> no memset needed.
  unsigned long long* atoms = (unsigned long long*)d_ws;

  static const int kDynLds = (HOFFS + 2 * Hsz) * 4;  // 132 KB
  hipFuncSetAttribute(reinterpret_cast<const void*>(p2_rnn),
                      hipFuncAttributeMaxDynamicSharedMemorySize, kDynLds);

  // Phase 1: out = x @ U + b
  p1_gemm<<<dim3(2048), dim3(256), 0, stream>>>(x, U, b, out);

  // Phase 2: in-place recurrence over T
  p2_rnn<<<dim3(256), dim3(512), kDynLds, stream>>>(h0, V, out, atoms);
}

// Round 5
// 1355.317 us; speedup vs baseline: 7.1354x; 1.0862x over previous
//
#include <hip/hip_runtime.h>
#include <hip/hip_bf16.h>

#define Bsz 64
#define Tsz 512
#define Isz 512
#define Hsz 512

// ---------------- Phase 1: xU = x @ U + bias ----------------
__global__ __launch_bounds__(256) void p1_gemm(const float* __restrict__ X,
                                               const float* __restrict__ U,
                                               const float* __restrict__ bias,
                                               float* __restrict__ out) {
  const int K = Isz, N = Hsz;
  __shared__ float As[32][128];
  __shared__ float Bs[32][64];
  const int MB = (Bsz * Tsz) / 128;
  int bm = blockIdx.x & (MB - 1);
  int bn = blockIdx.x >> 8;
  int t = threadIdx.x;
  int tx = t & 15, ty = t >> 4;

  float acc[8][4];
#pragma unroll
  for (int r = 0; r < 8; r++)
#pragma unroll
    for (int c = 0; c < 4; c++) acc[r][c] = 0.f;

  const float* Xb = X + (size_t)bm * 128 * K;
  const float* Ub = U + bn * 64;

  for (int k0 = 0; k0 < K; k0 += 32) {
    int ar = t >> 3, aq = t & 7;
#pragma unroll
    for (int i = 0; i < 4; i++) {
      int row = ar + 32 * i;
      float4 v = *(const float4*)&Xb[(size_t)row * K + k0 + 4 * aq];
      As[4 * aq + 0][row] = v.x;
      As[4 * aq + 1][row] = v.y;
      As[4 * aq + 2][row] = v.z;
      As[4 * aq + 3][row] = v.w;
    }
    int bkk = t >> 4, bq = t & 15;
#pragma unroll
    for (int i = 0; i < 2; i++) {
      int kk = bkk + 16 * i;
      *(float4*)&Bs[kk][4 * bq] = *(const float4*)&Ub[(size_t)(k0 + kk) * N + 4 * bq];
    }
    __syncthreads();
#pragma unroll
    for (int kk = 0; kk < 32; kk++) {
      float4 A0 = *(const float4*)&As[kk][ty * 8];
      float4 A1 = *(const float4*)&As[kk][ty * 8 + 4];
      float4 B0 = *(const float4*)&Bs[kk][tx * 4];
      float av[8] = {A0.x, A0.y, A0.z, A0.w, A1.x, A1.y, A1.z, A1.w};
      float bv[4] = {B0.x, B0.y, B0.z, B0.w};
#pragma unroll
      for (int r = 0; r < 8; r++)
#pragma unroll
        for (int c = 0; c < 4; c++) acc[r][c] += av[r] * bv[c];
    }
    __syncthreads();
  }

  float4 bias4 = *(const float4*)&bias[bn * 64 + tx * 4];
  float bb[4] = {bias4.x, bias4.y, bias4.z, bias4.w};
#pragma unroll
  for (int r = 0; r < 8; r++) {
    float4 o;
    o.x = acc[r][0] + bb[0];
    o.y = acc[r][1] + bb[1];
    o.z = acc[r][2] + bb[2];
    o.w = acc[r][3] + bb[3];
    *(float4*)&out[((size_t)bm * 128 + ty * 8 + r) * N + bn * 64 + tx * 4] = o;
  }
}

// ---------------- Phase 2: recurrence, col-major-swizzled V in LDS ----------
// 32 groups x 8 blocks; group g owns batches {2g,2g+1}; block jb owns V cols
// [64jb,+64). V slots: float4 F = k*16 + (cg ^ ((k>>4)&15)) holding
// V[k][4cg..4cg+3] -> staging is coalesced float4 reads + contiguous LDS
// writes; FMA-phase reads: each 8-lane phase group (fixed cq1, ks=0..7) spans
// all 32 banks -> conflict-free. h stored batch-INTERLEAVED (hA[k],hB[k])
// float2 pairs, swizzled fh(k), double-buffered (2x1024 floats) -> one b128
// h-read serves 2k x 2 batches; ONE __syncthreads per step.
// Thread (cq=t>>5, ks=t&31): 4 cols (cq*4..+3), 16 k (ks*16..+15), both
// batches. Per step/thread: 16 V-b128 + 8 h-b128 reads, 128 fmac.
// Reduction over 32 ks-lanes: 4 DPP stages (VALU pipe) + ds_swizzle xor16.
// Lanes ks<8 finalize output (b=ks>>2, j=ks&3): 1 tanh + store + tagged-atom
// store each. Cross-block exchange: (value,tag) packed in one 8B atom,
// relaxed agent-scope store; every thread polls its own k=t element for both
// batches; tag match implies value valid (no fences). 0xAA poison never
// matches a tag. 256 blocks @ 1/CU (136KB LDS) co-resident -> no deadlock.
#define NGrp 32
#define BPGrp 8
#define CPB 64

__device__ __forceinline__ float ftanh(float x) {
  float ax = fabsf(x);
  float e = __expf(2.f * ax);
  float r = 1.f - 2.f / (e + 1.f);
  return copysignf(r, x);
}

template <int CTRL>
__device__ __forceinline__ float dppadd(float x) {
  int y = __builtin_amdgcn_update_dpp(0, __float_as_int(x), CTRL, 0xf, 0xf, true);
  return x + __int_as_float(y);
}
__device__ __forceinline__ float swz16add(float x) {  // += lane^16 (within 32)
  return x + __int_as_float(
                 __builtin_amdgcn_ds_swizzle(__float_as_int(x), 0x401F));
}

__device__ __forceinline__ int fh(int k) {  // swizzled float idx of h-pair k
  int ks = k >> 4, kp = (k >> 1) & 7, e = k & 1;
  return (ks << 5) + (((kp ^ (ks & 7))) << 2) + (e << 1);
}

__device__ __forceinline__ unsigned long long packha(float h, int tag) {
  return (unsigned long long)__float_as_uint(h) |
         ((unsigned long long)(unsigned)tag << 32);
}

__global__ __launch_bounds__(512, 2) void p2_rnn(
    const float* __restrict__ h0, const float* __restrict__ V,
    float* __restrict__ out, unsigned long long* __restrict__ atoms) {
  extern __shared__ float sm[];  // V: 32768 floats; h: 2 x 1024 floats
  float4* __restrict__ Vl = (float4*)sm;
  float* __restrict__ hsm = sm + 32768;

  int bid = blockIdx.x;
  int g = bid & 31;   // members share bid%32 -> same bid%8 -> same XCD-ish
  int jb = bid >> 5;  // column-block 0..7
  int t = threadIdx.x;
  int cq = t >> 5, ks = t & 31;

  // ---- stage V: coalesced float4 global reads, conflict-free LDS writes ----
  for (int rep = 0; rep < 16; rep++) {
    int idx = rep * 512 + t;
    int k = idx >> 4, cg = idx & 15;
    float4 gv = *(const float4*)&V[(size_t)k * Hsz + CPB * jb + 4 * cg];
    Vl[k * 16 + (cg ^ ((k >> 4) & 15))] = gv;
  }
  // ---- initial h (parity 0), batch-interleaved ----
  {
    int k = t;
    float2 hv;
    hv.x = h0[(size_t)(2 * g + 0) * Hsz + k];
    hv.y = h0[(size_t)(2 * g + 1) * Hsz + k];
    *(float2*)&hsm[fh(k)] = hv;
  }
  __syncthreads();

  bool own = (ks < 8);
  int ob = ks >> 2, jj = ks & 3;
  int col = CPB * jb + cq * 4 + jj;
  size_t obase = ((size_t)(2 * g + ob) * Tsz) * Hsz + col;
  float xu = own ? out[obase] : 0.f;

  const int cs = cq ^ (ks & 15);
  const int k7 = ks & 7;
  const int pk = t;  // polled h element

  for (int s = 0; s < Tsz; s++) {
    float xun = 0.f;
    if (own && s + 1 < Tsz) xun = out[obase + (size_t)(s + 1) * Hsz];

    const float* hp = &hsm[(s & 1) * 1024 + (ks << 5)];
    const float4* vp = &Vl[(ks << 8) + cs];  // slot 256*ks + cs

    float aA0 = 0, aA1 = 0, aA2 = 0, aA3 = 0;
    float aB0 = 0, aB1 = 0, aB2 = 0, aB3 = 0;
#pragma unroll
    for (int kp = 0; kp < 8; kp++) {
      float4 h4 = *(const float4*)&hp[(kp ^ k7) << 2];  // hA,hB for k0,k0+1
      float4 v0 = vp[kp * 32];       // V[k0][4 cols]
      float4 v1 = vp[kp * 32 + 16];  // V[k0+1][4 cols]
      aA0 += v0.x * h4.x + v1.x * h4.z;  aB0 += v0.x * h4.y + v1.x * h4.w;
      aA1 += v0.y * h4.x + v1.y * h4.z;  aB1 += v0.y * h4.y + v1.y * h4.w;
      aA2 += v0.z * h4.x + v1.z * h4.z;  aB2 += v0.z * h4.y + v1.z * h4.w;
      aA3 += v0.w * h4.x + v1.w * h4.z;  aB3 += v0.w * h4.y + v1.w * h4.w;
    }
    // reduce over 32 ks-lanes: xor1, xor2 (quad_perm), ror4+ror8 (row), xor16
#define RED(x)                 \
  x = dppadd<0xB1>(x);         \
  x = dppadd<0x4E>(x);         \
  x = dppadd<0x124>(x);        \
  x = dppadd<0x128>(x);        \
  x = swz16add(x);
    RED(aA0) RED(aA1) RED(aA2) RED(aA3) RED(aB0) RED(aB1) RED(aB2) RED(aB3)
#undef RED

    int p = (s + 1) & 1;
    if (own) {
      float sum = ob ? ((jj & 2) ? ((jj & 1) ? aB3 : aB2) : ((jj & 1) ? aB1 : aB0))
                     : ((jj & 2) ? ((jj & 1) ? aA3 : aA2) : ((jj & 1) ? aA1 : aA0));
      float hv = ftanh(sum + xu);
      out[obase + (size_t)s * Hsz] = hv;
      if (s + 1 < Tsz)
        __hip_atomic_store(&atoms[((size_t)p * Bsz + 2 * g + ob) * Hsz + col],
                           packha(hv, s + 1), __ATOMIC_RELAXED,
                           __HIP_MEMORY_SCOPE_AGENT);
      xu = xun;
    }

    if (s + 1 < Tsz) {
      unsigned long long* q0 = &atoms[((size_t)p * Bsz + 2 * g + 0) * Hsz + pk];
      unsigned long long* q1 = &atoms[((size_t)p * Bsz + 2 * g + 1) * Hsz + pk];
      int want = s + 1;
      float hv0 = 0.f, hv1 = 0.f;
      bool d0 = false, d1 = false;
      int guard = 0;
      while (true) {
        if (!d0) {
          unsigned long long a = __hip_atomic_load(q0, __ATOMIC_RELAXED,
                                                   __HIP_MEMORY_SCOPE_AGENT);
          if ((int)(a >> 32) == want) { hv0 = __uint_as_float((unsigned)a); d0 = true; }
        }
        if (!d1) {
          unsigned long long a = __hip_atomic_load(q1, __ATOMIC_RELAXED,
                                                   __HIP_MEMORY_SCOPE_AGENT);
          if ((int)(a >> 32) == want) { hv1 = __uint_as_float((unsigned)a); d1 = true; }
        }
        if (d0 && d1) break;
        if (++guard > (1 << 20)) break;  // anti-hang: fail loud, not silent
      }
      float2 hv; hv.x = hv0; hv.y = hv1;
      *(float2*)&hsm[p * 1024 + fh(pk)] = hv;
      __syncthreads();  // single barrier per step (h double-buffered)
    }
  }
}

extern "C" void kernel_launch(void* const* d_in, const int* in_sizes, int n_in,
                              void* d_out, int out_size, void* d_ws, size_t ws_size,
                              hipStream_t stream) {
  const float* x  = (const float*)d_in[0];
  const float* h0 = (const float*)d_in[1];
  const float* U  = (const float*)d_in[2];
  const float* V  = (const float*)d_in[3];
  const float* b  = (const float*)d_in[4];
  float* out = (float*)d_out;
  // atoms: [2][Bsz][Hsz] x 8B = 512 KB of d_ws. Tag exact-match vs poison:
  // 0xAAAAAAAA never equals s+1 in [1,511] -> no memset needed.
  unsigned long long* atoms = (unsigned long long*)d_ws;

  static const int kDynLds = (32768 + 2 * 1024) * 4;  // 136 KB
  hipFuncSetAttribute(reinterpret_cast<const void*>(p2_rnn),
                      hipFuncAttributeMaxDynamicSharedMemorySize, kDynLds);

  // Phase 1: out = x @ U + b
  p1_gemm<<<dim3(2048), dim3(256), 0, stream>>>(x, U, b, out);

  // Phase 2: in-place recurrence over T
  p2_rnn<<<dim3(256), dim3(512), kDynLds, stream>>>(h0, V, out, atoms);
}

// Round 7
// 1315.732 us; speedup vs baseline: 7.3501x; 1.0301x over previous
//
#include <hip/hip_runtime.h>
#include <hip/hip_bf16.h>

#define Bsz 64
#define Tsz 512
#define Isz 512
#define Hsz 512

// ---------------- Phase 1: xU = x @ U + bias ----------------
__global__ __launch_bounds__(256) void p1_gemm(const float* __restrict__ X,
                                               const float* __restrict__ U,
                                               const float* __restrict__ bias,
                                               float* __restrict__ out) {
  const int K = Isz, N = Hsz;
  __shared__ float As[32][128];
  __shared__ float Bs[32][64];
  const int MB = (Bsz * Tsz) / 128;
  int bm = blockIdx.x & (MB - 1);
  int bn = blockIdx.x >> 8;
  int t = threadIdx.x;
  int tx = t & 15, ty = t >> 4;

  float acc[8][4];
#pragma unroll
  for (int r = 0; r < 8; r++)
#pragma unroll
    for (int c = 0; c < 4; c++) acc[r][c] = 0.f;

  const float* Xb = X + (size_t)bm * 128 * K;
  const float* Ub = U + bn * 64;

  for (int k0 = 0; k0 < K; k0 += 32) {
    int ar = t >> 3, aq = t & 7;
#pragma unroll
    for (int i = 0; i < 4; i++) {
      int row = ar + 32 * i;
      float4 v = *(const float4*)&Xb[(size_t)row * K + k0 + 4 * aq];
      As[4 * aq + 0][row] = v.x;
      As[4 * aq + 1][row] = v.y;
      As[4 * aq + 2][row] = v.z;
      As[4 * aq + 3][row] = v.w;
    }
    int bkk = t >> 4, bq = t & 15;
#pragma unroll
    for (int i = 0; i < 2; i++) {
      int kk = bkk + 16 * i;
      *(float4*)&Bs[kk][4 * bq] = *(const float4*)&Ub[(size_t)(k0 + kk) * N + 4 * bq];
    }
    __syncthreads();
#pragma unroll
    for (int kk = 0; kk < 32; kk++) {
      float4 A0 = *(const float4*)&As[kk][ty * 8];
      float4 A1 = *(const float4*)&As[kk][ty * 8 + 4];
      float4 B0 = *(const float4*)&Bs[kk][tx * 4];
      float av[8] = {A0.x, A0.y, A0.z, A0.w, A1.x, A1.y, A1.z, A1.w};
      float bv[4] = {B0.x, B0.y, B0.z, B0.w};
#pragma unroll
      for (int r = 0; r < 8; r++)
#pragma unroll
        for (int c = 0; c < 4; c++) acc[r][c] += av[r] * bv[c];
    }
    __syncthreads();
  }

  float4 bias4 = *(const float4*)&bias[bn * 64 + tx * 4];
  float bb[4] = {bias4.x, bias4.y, bias4.z, bias4.w};
#pragma unroll
  for (int r = 0; r < 8; r++) {
    float4 o;
    o.x = acc[r][0] + bb[0];
    o.y = acc[r][1] + bb[1];
    o.z = acc[r][2] + bb[2];
    o.w = acc[r][3] + bb[3];
    *(float4*)&out[((size_t)bm * 128 + ty * 8 + r) * N + bn * 64 + tx * 4] = o;
  }
}

// ---------------- Phase 2: recurrence — V in REGISTERS, h in LDS ------------
// 32 groups x 8 blocks; group g owns batches {2g,2g+1}; block jb owns V cols
// [64jb,+64). V is LOOP-INVARIANT: staged global->LDS (coalesced, swizzled),
// then hoisted into 64 named SCALAR float registers per thread, pinned with
// four 16-operand empty asm ("+v" on scalars; "+v" on float4 doesn't compile
// — r6 lesson). Scalar pins make LDS-remat illegal per component, and the
// in-loop hsm stores alias the staging region anyway -> V stays resident.
// h: double-buffered, batch-interleaved pairs at float-index
//   par*1024 + kp*128 + ks*4 + 2e   (k = 16ks + 2kp + e)
// -> per-kp wave read = 32 contiguous 16B lanes (+2-way cq broadcast) =
// conflict-free; write-back is a single 8-way-conflicted b64 (cheap).
// Reduction over 32 ks-lanes: 4 DPP stages + ds_swizzle xor16 (proven r5).
// Cross-block exchange: (value,tag) packed in one 8B atom, relaxed agent
// store; each thread polls its own k=t element for both batches; tag match
// implies value valid (no fences; 0xAA poison never matches a tag).
// 256 blocks @ 1/CU (136KB LDS) co-resident -> polls cannot deadlock.
#define NGrp 32
#define BPGrp 8
#define CPB 64

__device__ __forceinline__ float ftanh(float x) {
  float ax = fabsf(x);
  float e = __expf(2.f * ax);
  float r = 1.f - 2.f / (e + 1.f);
  return copysignf(r, x);
}

template <int CTRL>
__device__ __forceinline__ float dppadd(float x) {
  int y = __builtin_amdgcn_update_dpp(0, __float_as_int(x), CTRL, 0xf, 0xf, true);
  return x + __int_as_float(y);
}
__device__ __forceinline__ float swz16add(float x) {  // += lane^16 (within 32)
  return x + __int_as_float(
                 __builtin_amdgcn_ds_swizzle(__float_as_int(x), 0x401F));
}

__device__ __forceinline__ unsigned long long packha(float h, int tag) {
  return (unsigned long long)__float_as_uint(h) |
         ((unsigned long long)(unsigned)tag << 32);
}

__global__ __launch_bounds__(512, 2) void p2_rnn(
    const float* __restrict__ h0, const float* __restrict__ V,
    float* __restrict__ out, unsigned long long* __restrict__ atoms) {
  extern __shared__ float sm[];  // V stage: 32768 floats; h: 2 x 1024 floats
  float4* __restrict__ Vl = (float4*)sm;
  float* __restrict__ hsm = sm + 32768;

  int bid = blockIdx.x;
  int g = bid & 31;   // members share bid%32 -> same bid%8 -> same XCD-ish
  int jb = bid >> 5;  // column-block 0..7
  int t = threadIdx.x;
  int cq = t >> 5, ks = t & 31;

  // ---- stage V: coalesced float4 global reads, conflict-free LDS writes ----
  for (int rep = 0; rep < 16; rep++) {
    int idx = rep * 512 + t;
    int k = idx >> 4, cg = idx & 15;
    float4 gv = *(const float4*)&V[(size_t)k * Hsz + CPB * jb + 4 * cg];
    Vl[k * 16 + (cg ^ ((k >> 4) & 15))] = gv;
  }
  // ---- initial h (parity 0): k=t -> slot kp*128 + ks*4 + 2e ----
  {
    int k = t;
    int kw = (k & 15) >> 1, kse = k >> 4, e = k & 1;
    float2 hv;
    hv.x = h0[(size_t)(2 * g + 0) * Hsz + k];
    hv.y = h0[(size_t)(2 * g + 1) * Hsz + k];
    *(float2*)&hsm[kw * 128 + kse * 4 + 2 * e] = hv;
  }
  __syncthreads();

  // ---- hoist this thread's V slice into 64 named scalar registers, PIN ----
  const int cs = cq ^ (ks & 15);
  const float4* vp = &Vl[(ks << 8) + cs];
#define LOADV(i)                                                     \
  float4 tv##i = vp[(i) * 16];                                       \
  float v##i##x = tv##i.x, v##i##y = tv##i.y, v##i##z = tv##i.z,     \
        v##i##w = tv##i.w;
  LOADV(0) LOADV(1) LOADV(2) LOADV(3) LOADV(4) LOADV(5) LOADV(6) LOADV(7)
  LOADV(8) LOADV(9) LOADV(10) LOADV(11) LOADV(12) LOADV(13) LOADV(14) LOADV(15)
#undef LOADV
  asm volatile("" : "+v"(v0x), "+v"(v0y), "+v"(v0z), "+v"(v0w),
                    "+v"(v1x), "+v"(v1y), "+v"(v1z), "+v"(v1w),
                    "+v"(v2x), "+v"(v2y), "+v"(v2z), "+v"(v2w),
                    "+v"(v3x), "+v"(v3y), "+v"(v3z), "+v"(v3w));
  asm volatile("" : "+v"(v4x), "+v"(v4y), "+v"(v4z), "+v"(v4w),
                    "+v"(v5x), "+v"(v5y), "+v"(v5z), "+v"(v5w),
                    "+v"(v6x), "+v"(v6y), "+v"(v6z), "+v"(v6w),
                    "+v"(v7x), "+v"(v7y), "+v"(v7z), "+v"(v7w));
  asm volatile("" : "+v"(v8x), "+v"(v8y), "+v"(v8z), "+v"(v8w),
                    "+v"(v9x), "+v"(v9y), "+v"(v9z), "+v"(v9w),
                    "+v"(v10x), "+v"(v10y), "+v"(v10z), "+v"(v10w),
                    "+v"(v11x), "+v"(v11y), "+v"(v11z), "+v"(v11w));
  asm volatile("" : "+v"(v12x), "+v"(v12y), "+v"(v12z), "+v"(v12w),
                    "+v"(v13x), "+v"(v13y), "+v"(v13z), "+v"(v13w),
                    "+v"(v14x), "+v"(v14y), "+v"(v14z), "+v"(v14w),
                    "+v"(v15x), "+v"(v15y), "+v"(v15z), "+v"(v15w));

  bool own = (ks < 8);
  int ob = ks >> 2, jj = ks & 3;
  int col = CPB * jb + cq * 4 + jj;
  size_t obase = ((size_t)(2 * g + ob) * Tsz) * Hsz + col;
  float xu = own ? out[obase] : 0.f;

  const int ks4 = ks * 4;
  const int pk = t;  // polled h element
  const int hwidx = ((pk & 15) >> 1) * 128 + (pk >> 4) * 4 + 2 * (pk & 1);

  for (int s = 0; s < Tsz; s++) {
    float xun = 0.f;
    if (own && s + 1 < Tsz) xun = out[obase + (size_t)(s + 1) * Hsz];

    const float* hp = &hsm[(s & 1) * 1024 + ks4];

    float aA0 = 0, aA1 = 0, aA2 = 0, aA3 = 0;
    float aB0 = 0, aB1 = 0, aB2 = 0, aB3 = 0;
#define STEPK(kp, a, b)                                                        \
  {                                                                            \
    float4 h4 = *(const float4*)&hp[(kp) * 128];                               \
    aA0 += v##a##x * h4.x + v##b##x * h4.z;                                    \
    aB0 += v##a##x * h4.y + v##b##x * h4.w;                                    \
    aA1 += v##a##y * h4.x + v##b##y * h4.z;                                    \
    aB1 += v##a##y * h4.y + v##b##y * h4.w;                                    \
    aA2 += v##a##z * h4.x + v##b##z * h4.z;                                    \
    aB2 += v##a##z * h4.y + v##b##z * h4.w;                                    \
    aA3 += v##a##w * h4.x + v##b##w * h4.z;                                    \
    aB3 += v##a##w * h4.y + v##b##w * h4.w;                                    \
  }
    STEPK(0, 0, 1)  STEPK(1, 2, 3)   STEPK(2, 4, 5)   STEPK(3, 6, 7)
    STEPK(4, 8, 9)  STEPK(5, 10, 11) STEPK(6, 12, 13) STEPK(7, 14, 15)
#undef STEPK

    // reduce over 32 ks-lanes: xor1, xor2 (quad_perm), ror4+ror8 (row), xor16
#define RED(x)                 \
  x = dppadd<0xB1>(x);         \
  x = dppadd<0x4E>(x);         \
  x = dppadd<0x124>(x);        \
  x = dppadd<0x128>(x);        \
  x = swz16add(x);
    RED(aA0) RED(aA1) RED(aA2) RED(aA3) RED(aB0) RED(aB1) RED(aB2) RED(aB3)
#undef RED

    int p = (s + 1) & 1;
    if (own) {
      float sum = ob ? ((jj & 2) ? ((jj & 1) ? aB3 : aB2) : ((jj & 1) ? aB1 : aB0))
                     : ((jj & 2) ? ((jj & 1) ? aA3 : aA2) : ((jj & 1) ? aA1 : aA0));
      float hv = ftanh(sum + xu);
      out[obase + (size_t)s * Hsz] = hv;
      if (s + 1 < Tsz)
        __hip_atomic_store(&atoms[((size_t)p * Bsz + 2 * g + ob) * Hsz + col],
                           packha(hv, s + 1), __ATOMIC_RELAXED,
                           __HIP_MEMORY_SCOPE_AGENT);
      xu = xun;
    }

    if (s + 1 < Tsz) {
      unsigned long long* q0 = &atoms[((size_t)p * Bsz + 2 * g + 0) * Hsz + pk];
      unsigned long long* q1 = &atoms[((size_t)p * Bsz + 2 * g + 1) * Hsz + pk];
      int want = s + 1;
      float hv0 = 0.f, hv1 = 0.f;
      bool d0 = false, d1 = false;
      int guard = 0;
      while (true) {
        if (!d0) {
          unsigned long long a = __hip_atomic_load(q0, __ATOMIC_RELAXED,
                                                   __HIP_MEMORY_SCOPE_AGENT);
          if ((int)(a >> 32) == want) { hv0 = __uint_as_float((unsigned)a); d0 = true; }
        }
        if (!d1) {
          unsigned long long a = __hip_atomic_load(q1, __ATOMIC_RELAXED,
                                                   __HIP_MEMORY_SCOPE_AGENT);
          if ((int)(a >> 32) == want) { hv1 = __uint_as_float((unsigned)a); d1 = true; }
        }
        if (d0 && d1) break;
        if (++guard > (1 << 20)) break;  // anti-hang: fail loud, not silent
      }
      float2 hv; hv.x = hv0; hv.y = hv1;
      *(float2*)&hsm[p * 1024 + hwidx] = hv;
      __syncthreads();  // single barrier per step (h double-buffered)
    }
  }
}

extern "C" void kernel_launch(void* const* d_in, const int* in_sizes, int n_in,
                              void* d_out, int out_size, void* d_ws, size_t ws_size,
                              hipStream_t stream) {
  const float* x  = (const float*)d_in[0];
  const float* h0 = (const float*)d_in[1];
  const float* U  = (const float*)d_in[2];
  const float* V  = (const float*)d_in[3];
  const float* b  = (const float*)d_in[4];
  float* out = (float*)d_out;
  // atoms: [2][Bsz][Hsz] x 8B = 512 KB of d_ws. Tag exact-match vs poison:
  // 0xAAAAAAAA never equals s+1 in [1,511] -> no memset needed.
  unsigned long long* atoms = (unsigned long long*)d_ws;

  static const int kDynLds = (32768 + 2 * 1024) * 4;  // 136 KB
  (void)hipFuncSetAttribute(reinterpret_cast<const void*>(p2_rnn),
                            hipFuncAttributeMaxDynamicSharedMemorySize, kDynLds);

  // Phase 1: out = x @ U + b
  p1_gemm<<<dim3(2048), dim3(256), 0, stream>>>(x, U, b, out);

  // Phase 2: in-place recurrence over T
  p2_rnn<<<dim3(256), dim3(512), kDynLds, stream>>>(h0, V, out, atoms);
}